// Round 7
// baseline (424.621 us; speedup 1.0000x reference)
//
#include <hip/hip_runtime.h>
#include <math.h>

#define NBINS 28
#define L2E 1.44269504088896340736f

#define EXP2F(x) __builtin_amdgcn_exp2f(x)
#define RCPF(x)  __builtin_amdgcn_rcpf(x)

// workspace float offsets.  ROW-MAJOR, prescaled (proven layout):
//   WS_W1[f*16+j] = W1[f][j] * -log2e     (f=0..7,  j=0..15)
//   WS_W2[k*16+j] = W2[k][j] * -log2e     (k=0..15, j=0..15)
// R7: weights served from LDS (staged once per block), NOT SGPRs.
// R1/R5/R6 all plateaued at 123-129us: the SGPR path re-fetches 433
// weights per wave in ~27 dependency groups and the SGPR file caps
// prefetch depth at ~4 groups -> exposed load-to-use latency that ~3
// waves/SIMD can't hide, invariant to math scheduling.  LDS broadcast
// ds_read_b128 (same addr across wave = conflict-free) pipelines
// multi-outstanding on the separate DS pipe: ~108 reads/thread x 61
// waves/CU x 12cyc ~= 33us/CU, overlappable with the ~30us VALU floor.
// Unlike R0: row-major scalar consumption (no float4 repack bloat),
// 4 rows/thread, zero sched fences.
#define WS_TBL 0    // 40 floats: ml_table[d-1] = exp(ml_mlp(d) - 0.25 d), d=1..40
#define WS_W1  64   // 128 floats, row-major, * -log2e
#define WS_B1  192  // 16, * -log2e
#define WS_W2  208  // 256 floats, row-major, * -log2e
#define WS_B2  464  // 16, * -log2e
#define WS_W3  480  // 16, * +log2e
#define WS_B3  496  // 1, * +log2e
#define WS_TOT 512

__global__ void prep_kernel(const float* __restrict__ mh_W1, const float* __restrict__ mh_b1,
                            const float* __restrict__ mh_W2, const float* __restrict__ mh_b2,
                            const float* __restrict__ mh_W3, const float* __restrict__ mh_b3,
                            const float* __restrict__ ml_W1, const float* __restrict__ ml_b1,
                            const float* __restrict__ ml_W2, const float* __restrict__ ml_b2,
                            const float* __restrict__ ml_W3, const float* __restrict__ ml_b3,
                            float* __restrict__ ws, float* __restrict__ out_bins) {
    const int t = threadIdx.x;  // 64 threads
    for (int k = t; k < 128; k += 64) ws[WS_W1 + k] = -L2E * mh_W1[k];
    for (int k = t; k < 16;  k += 64) ws[WS_B1 + k] = -L2E * mh_b1[k];
    for (int k = t; k < 256; k += 64) ws[WS_W2 + k] = -L2E * mh_W2[k];
    for (int k = t; k < 16;  k += 64) ws[WS_B2 + k] = -L2E * mh_b2[k];
    for (int k = t; k < 16;  k += 64) ws[WS_W3 + k] =  L2E * mh_W3[k];
    if (t == 0) ws[WS_B3] = L2E * mh_b3[0];

    if (t < 40) {
        const float x = (float)(t + 1);
        float h1[16], h2[16];
        #pragma unroll
        for (int j = 0; j < 16; ++j)
            h1[j] = 1.0f / (1.0f + expf(-(x * ml_W1[j] + ml_b1[j])));
        #pragma unroll
        for (int j = 0; j < 16; ++j) {
            float a = ml_b2[j];
            #pragma unroll
            for (int k = 0; k < 16; ++k) a = fmaf(h1[k], ml_W2[k * 16 + j], a);
            h2[j] = 1.0f / (1.0f + expf(-a));
        }
        float phi = ml_b3[0];
        #pragma unroll
        for (int k = 0; k < 16; ++k) phi = fmaf(h2[k], ml_W3[k], phi);
        const float sc = expf(phi - 0.25f * x);
        ws[WS_TBL + t] = sc;
        if (t < NBINS) out_bins[t] = sc;  // dl2_scores term of output 1
    }
}

// 4 rows/thread, rows innermost (each weight read feeds 4 FMAs).
// Weight fetch: float4 broadcast reads from LDS; scalar fmaf math
// identical to the verified R6 body.  All register arrays statically
// indexed under full unroll; no sched fences (let the scheduler batch
// ds_reads with counted lgkmcnt).
__global__ __launch_bounds__(256) void main_kernel(
        const float4* __restrict__ x4,
        const int4* __restrict__ dl4p,
        const int4* __restrict__ ml4p,
        const float* __restrict__ ws,
        float4* __restrict__ out4,
        float* __restrict__ out_bins,
        int nquad) {
    __shared__ float sw[WS_TOT];
    __shared__ float s_bins[4 * NBINS];
    const int tid = threadIdx.x;
    #pragma unroll
    for (int k = tid; k < WS_TOT; k += 256) sw[k] = ws[k];
    if (tid < 4 * NBINS) s_bins[tid] = 0.0f;
    __syncthreads();

    const int q = blockIdx.x * 256 + tid;
    const bool active = (q < nquad);
    const int qc = active ? q : 0;   // clamp loads; discard via `active` at store

    float xf[4][8];
    #pragma unroll
    for (int r = 0; r < 4; ++r) {
        const float4 a = x4[8 * qc + 2 * r + 0];
        const float4 b = x4[8 * qc + 2 * r + 1];
        xf[r][0] = a.x; xf[r][1] = a.y; xf[r][2] = a.z; xf[r][3] = a.w;
        xf[r][4] = b.x; xf[r][5] = b.y; xf[r][6] = b.z; xf[r][7] = b.w;
    }
    const int4 dl = dl4p[qc];
    const int4 ml = ml4p[qc];
    const int dlv[4] = {dl.x, dl.y, dl.z, dl.w};
    const int mlv[4] = {ml.x, ml.y, ml.z, ml.w};

    // ---- layer 1: 8 -> 16 (weights prescaled by -log2e, LDS-broadcast) ----
    float u[4][16];
    #pragma unroll
    for (int jc = 0; jc < 16; jc += 4) {
        const float4 b4 = *(const float4*)&sw[WS_B1 + jc];
        const float bb[4] = {b4.x, b4.y, b4.z, b4.w};
        #pragma unroll
        for (int jj = 0; jj < 4; ++jj) {
            #pragma unroll
            for (int r = 0; r < 4; ++r) u[r][jc + jj] = bb[jj];
        }
    }
    #pragma unroll
    for (int f = 0; f < 8; ++f) {
        #pragma unroll
        for (int jc = 0; jc < 16; jc += 4) {
            const float4 w4 = *(const float4*)&sw[WS_W1 + f * 16 + jc];
            const float wv[4] = {w4.x, w4.y, w4.z, w4.w};
            #pragma unroll
            for (int jj = 0; jj < 4; ++jj) {
                #pragma unroll
                for (int r = 0; r < 4; ++r)
                    u[r][jc + jj] = fmaf(xf[r][f], wv[jj], u[r][jc + jj]);
            }
        }
    }
    float h[4][16];
    #pragma unroll
    for (int j = 0; j < 16; ++j) {
        #pragma unroll
        for (int r = 0; r < 4; ++r) h[r][j] = RCPF(1.0f + EXP2F(u[r][j]));
    }

    // ---- layer 2: 16 -> 16 ----
    float v[4][16];
    #pragma unroll
    for (int jc = 0; jc < 16; jc += 4) {
        const float4 b4 = *(const float4*)&sw[WS_B2 + jc];
        const float bb[4] = {b4.x, b4.y, b4.z, b4.w};
        #pragma unroll
        for (int jj = 0; jj < 4; ++jj) {
            #pragma unroll
            for (int r = 0; r < 4; ++r) v[r][jc + jj] = bb[jj];
        }
    }
    #pragma unroll
    for (int k = 0; k < 16; ++k) {
        #pragma unroll
        for (int jc = 0; jc < 16; jc += 4) {
            const float4 w4 = *(const float4*)&sw[WS_W2 + k * 16 + jc];
            const float wv[4] = {w4.x, w4.y, w4.z, w4.w};
            #pragma unroll
            for (int jj = 0; jj < 4; ++jj) {
                #pragma unroll
                for (int r = 0; r < 4; ++r)
                    v[r][jc + jj] = fmaf(h[r][k], wv[jj], v[r][jc + jj]);
            }
        }
    }

    // ---- layer 3 + psi ----
    const float pb = sw[WS_B3];          // prescaled by +log2e
    float phi[4] = {pb, pb, pb, pb};
    #pragma unroll
    for (int jc = 0; jc < 16; jc += 4) {
        const float4 w4 = *(const float4*)&sw[WS_W3 + jc];  // +log2e
        const float wv[4] = {w4.x, w4.y, w4.z, w4.w};
        #pragma unroll
        for (int jj = 0; jj < 4; ++jj) {
            #pragma unroll
            for (int r = 0; r < 4; ++r)
                phi[r] = fmaf(RCPF(1.0f + EXP2F(v[r][jc + jj])), wv[jj], phi[r]);
        }
    }
    float sc[4];
    #pragma unroll
    for (int r = 0; r < 4; ++r)
        sc[r] = EXP2F(fmaf((float)dlv[r], -0.25f * L2E, phi[r]));

    // ---- epilogue ----
    if (active) {
        float ov[4];
        #pragma unroll
        for (int r = 0; r < 4; ++r) {
            const int i = min(max(dlv[r], 1), 40) - 1;
            ov[r] = sc[r] + ((dlv[r] == mlv[r]) ? sw[WS_TBL + i] : 0.0f);
        }
        float4 o; o.x = ov[0]; o.y = ov[1]; o.z = ov[2]; o.w = ov[3];
        out4[q] = o;
        float* myb = &s_bins[(tid >> 6) * NBINS];
        #pragma unroll
        for (int r = 0; r < 4; ++r)
            if (dlv[r] >= 1 && dlv[r] <= NBINS)
                unsafeAtomicAdd(&myb[dlv[r] - 1], sc[r]);
    }

    __syncthreads();
    if (tid < NBINS) {
        const float bsum = s_bins[tid] + s_bins[NBINS + tid] +
                           s_bins[2 * NBINS + tid] + s_bins[3 * NBINS + tid];
        unsafeAtomicAdd(&out_bins[tid], bsum);
    }
}

extern "C" void kernel_launch(void* const* d_in, const int* in_sizes, int n_in,
                              void* d_out, int out_size, void* d_ws, size_t ws_size,
                              hipStream_t stream) {
    const int n = in_sizes[0] / 8;  // N rows (N = 4e6, divisible by 4)

    const float* x_feat = (const float*)d_in[0];
    const float* mh_W1  = (const float*)d_in[1];
    const float* mh_b1  = (const float*)d_in[2];
    const float* mh_W2  = (const float*)d_in[3];
    const float* mh_b2  = (const float*)d_in[4];
    const float* mh_W3  = (const float*)d_in[5];
    const float* mh_b3  = (const float*)d_in[6];
    const float* ml_W1  = (const float*)d_in[7];
    const float* ml_b1  = (const float*)d_in[8];
    const float* ml_W2  = (const float*)d_in[9];
    const float* ml_b2  = (const float*)d_in[10];
    const float* ml_W3  = (const float*)d_in[11];
    const float* ml_b3  = (const float*)d_in[12];
    const int* del_lens = (const int*)d_in[13];
    const int* mh_len   = (const int*)d_in[14];

    float* out      = (float*)d_out;
    float* out_bins = out + n;  // last 28 elements of d_out
    float* ws       = (float*)d_ws;

    prep_kernel<<<dim3(1), dim3(64), 0, stream>>>(
        mh_W1, mh_b1, mh_W2, mh_b2, mh_W3, mh_b3,
        ml_W1, ml_b1, ml_W2, ml_b2, ml_W3, ml_b3,
        ws, out_bins);

    const int nquad = n / 4;
    const int nblocks = (nquad + 255) / 256;
    main_kernel<<<dim3(nblocks), dim3(256), 0, stream>>>(
        (const float4*)x_feat, (const int4*)del_lens, (const int4*)mh_len,
        ws, (float4*)out, out_bins, nquad);
}

// Round 9
// 311.576 us; speedup vs baseline: 1.3628x; 1.3628x over previous
//
#include <hip/hip_runtime.h>
#include <math.h>

#define NBINS 28
#define L2E 1.44269504088896340736f

#define EXP2F(x) __builtin_amdgcn_exp2f(x)
#define RCPF(x)  __builtin_amdgcn_rcpf(x)

// NOTE (R8 lesson): in HIP mode the AMDGPU builtins' half type is
// __fp16, not _Float16 — cvt_pkrtz returns __fp16 ext_vector_type(2).
typedef __fp16 h2t __attribute__((ext_vector_type(2)));

// fdot2: d = a.x*b.x + a.y*b.y + c  (f16 inputs, f32 accumulate, 1 VALU slot)
static __device__ __forceinline__ float fdot2(h2t a, h2t b, float c) {
    return __builtin_amdgcn_fdot2(a, b, c, false);
}
static __device__ __forceinline__ h2t pkx(float lo, float hi) {
    return __builtin_amdgcn_cvt_pkrtz(lo, hi);   // .x = lo, .y = hi
}
static __device__ __forceinline__ h2t asH2(float f) {
    union { float f; h2t h; } u; u.f = f; return u.h;
}

// workspace float offsets.
// f32 region (proven R1 layout, kept for biases/W3/table):
#define WS_TBL 0    // 40 floats: ml_table[d-1] = exp(ml_mlp(d) - 0.25 d), d=1..40
#define WS_W1  64   // 128 floats, row-major, * -log2e   (unused by f16 path)
#define WS_B1  192  // 16, * -log2e
#define WS_W2  208  // 256 floats, row-major, * -log2e   (unused by f16 path)
#define WS_B2  464  // 16, * -log2e
#define WS_W3  480  // 16, * +log2e
#define WS_B3  496  // 1, * +log2e
// packed-f16 region: weight PAIRS along the reduction dim, one dword each.
//   WP_W1[f2*16+j] = pack(f16(-L2E*W1[2f2][j]), f16(-L2E*W1[2f2+1][j]))  f2=0..3
//   WP_W2[k2*16+j] = pack(f16(-L2E*W2[2k2][j]), f16(-L2E*W2[2k2+1][j]))  k2=0..7
// 241 uniform weight dwords total (vs 433 f32) -> ~15 s_load dependency
// groups instead of 27, each dword feeding 2 MACs via v_dot2_f32_f16.
#define WP_W1  512  // 64 dwords
#define WP_W2  576  // 128 dwords
#define WS_TOT 704

__global__ void prep_kernel(const float* __restrict__ mh_W1, const float* __restrict__ mh_b1,
                            const float* __restrict__ mh_W2, const float* __restrict__ mh_b2,
                            const float* __restrict__ mh_W3, const float* __restrict__ mh_b3,
                            const float* __restrict__ ml_W1, const float* __restrict__ ml_b1,
                            const float* __restrict__ ml_W2, const float* __restrict__ ml_b2,
                            const float* __restrict__ ml_W3, const float* __restrict__ ml_b3,
                            float* __restrict__ ws, float* __restrict__ out_bins) {
    const int t = threadIdx.x;  // 64 threads
    for (int k = t; k < 128; k += 64) ws[WS_W1 + k] = -L2E * mh_W1[k];
    for (int k = t; k < 16;  k += 64) ws[WS_B1 + k] = -L2E * mh_b1[k];
    for (int k = t; k < 256; k += 64) ws[WS_W2 + k] = -L2E * mh_W2[k];
    for (int k = t; k < 16;  k += 64) ws[WS_B2 + k] = -L2E * mh_b2[k];
    for (int k = t; k < 16;  k += 64) ws[WS_W3 + k] =  L2E * mh_W3[k];
    if (t == 0) ws[WS_B3] = L2E * mh_b3[0];

    // packed f16 pairs (RNE via scalar cast)
    for (int k = t; k < 64; k += 64) {       // k = f2*16 + j
        const int f2 = k >> 4, j = k & 15;
        union { __fp16 h[2]; float f; } u;
        u.h[0] = (__fp16)(-L2E * mh_W1[(2 * f2)     * 16 + j]);
        u.h[1] = (__fp16)(-L2E * mh_W1[(2 * f2 + 1) * 16 + j]);
        ws[WP_W1 + k] = u.f;
    }
    for (int k = t; k < 128; k += 64) {      // k = k2*16 + j
        const int k2 = k >> 4, j = k & 15;
        union { __fp16 h[2]; float f; } u;
        u.h[0] = (__fp16)(-L2E * mh_W2[(2 * k2)     * 16 + j]);
        u.h[1] = (__fp16)(-L2E * mh_W2[(2 * k2 + 1) * 16 + j]);
        ws[WP_W2 + k] = u.f;
    }

    if (t < 40) {
        const float x = (float)(t + 1);
        float h1[16], h2[16];
        #pragma unroll
        for (int j = 0; j < 16; ++j)
            h1[j] = 1.0f / (1.0f + expf(-(x * ml_W1[j] + ml_b1[j])));
        #pragma unroll
        for (int j = 0; j < 16; ++j) {
            float a = ml_b2[j];
            #pragma unroll
            for (int k = 0; k < 16; ++k) a = fmaf(h1[k], ml_W2[k * 16 + j], a);
            h2[j] = 1.0f / (1.0f + expf(-a));
        }
        float phi = ml_b3[0];
        #pragma unroll
        for (int k = 0; k < 16; ++k) phi = fmaf(h2[k], ml_W3[k], phi);
        const float sc = expf(phi - 0.25f * x);
        ws[WS_TBL + t] = sc;
        if (t < NBINS) out_bins[t] = sc;  // dl2_scores term of output 1
    }
}

// 2 rows/thread (proven R1 geometry).  MAC engine = v_dot2_f32_f16:
// inputs/hiddens packed to f16 pairs (cvt_pkrtz), weights consumed as
// wave-uniform packed dwords (SGPR path), accumulation in f32.
// L1: 4x16 dot2/row (was 8x16 fma); L2: 8x16 dot2/row (was 16x16 fma)
// -> ~35% fewer VALU slots and ~45% fewer scalar-load groups than R1.
// No sched fences (R6: neutral); tripwire for R7-style spill = WRITE_SIZE.
__global__ __launch_bounds__(256) void main_kernel(
        const float4* __restrict__ x4,
        const int2* __restrict__ dl2p,
        const int2* __restrict__ ml2p,
        const float* __restrict__ ws,
        float2* __restrict__ out2,
        float* __restrict__ out_bins,
        int npair) {
    __shared__ float s_tbl[40];
    __shared__ float s_bins[4 * NBINS];
    const int tid = threadIdx.x;
    if (tid < 40) s_tbl[tid] = ws[WS_TBL + tid];
    if (tid < 4 * NBINS) s_bins[tid] = 0.0f;
    __syncthreads();

    const int p = blockIdx.x * 256 + tid;
    const bool active = (p < npair);
    const int pc = active ? p : 0;   // clamp loads; discard via `active` at store

    const float4 a0 = x4[4 * pc + 0];
    const float4 a1 = x4[4 * pc + 1];
    const float4 b0 = x4[4 * pc + 2];
    const float4 b1 = x4[4 * pc + 3];
    const int2 dl = dl2p[pc];
    const int2 ml = ml2p[pc];

    // x packed to f16 pairs along the feature dim (4 pairs per row)
    h2t xp0[4], xp1[4];
    xp0[0] = pkx(a0.x, a0.y); xp0[1] = pkx(a0.z, a0.w);
    xp0[2] = pkx(a1.x, a1.y); xp0[3] = pkx(a1.z, a1.w);
    xp1[0] = pkx(b0.x, b0.y); xp1[1] = pkx(b0.z, b0.w);
    xp1[2] = pkx(b1.x, b1.y); xp1[3] = pkx(b1.z, b1.w);

    // ---- layer 1: 8 -> 16 via dot2 (weights prescaled by -log2e) ----
    float u0[16], u1[16];
    #pragma unroll
    for (int j = 0; j < 16; ++j) {
        const float b = ws[WS_B1 + j];
        u0[j] = b; u1[j] = b;
    }
    #pragma unroll
    for (int f2 = 0; f2 < 4; ++f2) {
        #pragma unroll
        for (int j = 0; j < 16; ++j) {
            const h2t w = asH2(ws[WP_W1 + f2 * 16 + j]);
            u0[j] = fdot2(xp0[f2], w, u0[j]);
            u1[j] = fdot2(xp1[f2], w, u1[j]);
        }
    }
    // sigmoid in f32, then pack h pairs along k
    h2t hp0[8], hp1[8];
    #pragma unroll
    for (int k2 = 0; k2 < 8; ++k2) {
        const float h0a = RCPF(1.0f + EXP2F(u0[2 * k2]));
        const float h0b = RCPF(1.0f + EXP2F(u0[2 * k2 + 1]));
        const float h1a = RCPF(1.0f + EXP2F(u1[2 * k2]));
        const float h1b = RCPF(1.0f + EXP2F(u1[2 * k2 + 1]));
        hp0[k2] = pkx(h0a, h0b);
        hp1[k2] = pkx(h1a, h1b);
    }

    // ---- layer 2: 16 -> 16 via dot2 ----
    float v0[16], v1[16];
    #pragma unroll
    for (int j = 0; j < 16; ++j) {
        const float b = ws[WS_B2 + j];
        v0[j] = b; v1[j] = b;
    }
    #pragma unroll
    for (int k2 = 0; k2 < 8; ++k2) {
        #pragma unroll
        for (int j = 0; j < 16; ++j) {
            const h2t w = asH2(ws[WP_W2 + k2 * 16 + j]);
            v0[j] = fdot2(hp0[k2], w, v0[j]);
            v1[j] = fdot2(hp1[k2], w, v1[j]);
        }
    }

    // ---- layer 3 + psi (f32, as verified R1 body) ----
    float phi0 = ws[WS_B3], phi1 = phi0;   // prescaled by +log2e
    #pragma unroll
    for (int j = 0; j < 16; ++j) {
        const float w3 = ws[WS_W3 + j];    // prescaled by +log2e
        phi0 = fmaf(RCPF(1.0f + EXP2F(v0[j])), w3, phi0);
        phi1 = fmaf(RCPF(1.0f + EXP2F(v1[j])), w3, phi1);
    }
    const float sc0 = EXP2F(fmaf((float)dl.x, -0.25f * L2E, phi0));
    const float sc1 = EXP2F(fmaf((float)dl.y, -0.25f * L2E, phi1));

    // ---- epilogue ----
    if (active) {
        const int i0 = min(max(dl.x, 1), 40) - 1;
        const int i1 = min(max(dl.y, 1), 40) - 1;
        const float add0 = (dl.x == ml.x) ? s_tbl[i0] : 0.0f;
        const float add1 = (dl.y == ml.y) ? s_tbl[i1] : 0.0f;
        out2[p] = make_float2(sc0 + add0, sc1 + add1);
        float* myb = &s_bins[(tid >> 6) * NBINS];
        if (dl.x >= 1 && dl.x <= NBINS) unsafeAtomicAdd(&myb[dl.x - 1], sc0);
        if (dl.y >= 1 && dl.y <= NBINS) unsafeAtomicAdd(&myb[dl.y - 1], sc1);
    }

    __syncthreads();
    if (tid < NBINS) {
        const float bsum = s_bins[tid] + s_bins[NBINS + tid] +
                           s_bins[2 * NBINS + tid] + s_bins[3 * NBINS + tid];
        unsafeAtomicAdd(&out_bins[tid], bsum);
    }
}

extern "C" void kernel_launch(void* const* d_in, const int* in_sizes, int n_in,
                              void* d_out, int out_size, void* d_ws, size_t ws_size,
                              hipStream_t stream) {
    const int n = in_sizes[0] / 8;  // N rows (even)

    const float* x_feat = (const float*)d_in[0];
    const float* mh_W1  = (const float*)d_in[1];
    const float* mh_b1  = (const float*)d_in[2];
    const float* mh_W2  = (const float*)d_in[3];
    const float* mh_b2  = (const float*)d_in[4];
    const float* mh_W3  = (const float*)d_in[5];
    const float* mh_b3  = (const float*)d_in[6];
    const float* ml_W1  = (const float*)d_in[7];
    const float* ml_b1  = (const float*)d_in[8];
    const float* ml_W2  = (const float*)d_in[9];
    const float* ml_b2  = (const float*)d_in[10];
    const float* ml_W3  = (const float*)d_in[11];
    const float* ml_b3  = (const float*)d_in[12];
    const int* del_lens = (const int*)d_in[13];
    const int* mh_len   = (const int*)d_in[14];

    float* out      = (float*)d_out;
    float* out_bins = out + n;  // last 28 elements of d_out
    float* ws       = (float*)d_ws;

    prep_kernel<<<dim3(1), dim3(64), 0, stream>>>(
        mh_W1, mh_b1, mh_W2, mh_b2, mh_W3, mh_b3,
        ml_W1, ml_b1, ml_W2, ml_b2, ml_W3, ml_b3,
        ws, out_bins);

    const int npair = n / 2;
    const int nblocks = (npair + 255) / 256;
    main_kernel<<<dim3(nblocks), dim3(256), 0, stream>>>(
        (const float4*)x_feat, (const int2*)del_lens, (const int2*)mh_len,
        ws, (float2*)out, out_bins, npair);
}

// Round 10
// 267.385 us; speedup vs baseline: 1.5881x; 1.1653x over previous
//
#include <hip/hip_runtime.h>
#include <math.h>

#define NBINS 28
#define L2E 1.44269504088896340736f

#define EXP2F(x) __builtin_amdgcn_exp2f(x)
#define RCPF(x)  __builtin_amdgcn_rcpf(x)

// R8 lesson: in HIP mode the AMDGPU builtins' half type is __fp16.
typedef __fp16 h2t __attribute__((ext_vector_type(2)));

// fdot2: d = a.x*b.x + a.y*b.y + c  (f16 inputs, f32 accumulate, 1 VALU slot)
static __device__ __forceinline__ float fdot2(h2t a, h2t b, float c) {
    return __builtin_amdgcn_fdot2(a, b, c, false);
}
static __device__ __forceinline__ h2t pkx(float lo, float hi) {
    return __builtin_amdgcn_cvt_pkrtz(lo, hi);   // .x = lo, .y = hi
}
static __device__ __forceinline__ h2t asH2(float f) {
    union { float f; h2t h; } u; u.f = f; return u.h;
}

// workspace float offsets (R9 layout: f32 region + packed-f16 pairs).
#define WS_TBL 0    // 40 floats: ml_table[d-1] = exp(ml_mlp(d) - 0.25 d), d=1..40
#define WS_W1  64   // 128 floats, row-major, * -log2e   (unused by f16 path)
#define WS_B1  192  // 16, * -log2e
#define WS_W2  208  // 256 floats, row-major, * -log2e   (unused by f16 path)
#define WS_B2  464  // 16, * -log2e
#define WS_W3  480  // 16, * +log2e
#define WS_B3  496  // 1, * +log2e
#define WP_W1  512  // 64 dwords:  pack(f16(-L2E*W1[2f2][j]), f16(-L2E*W1[2f2+1][j]))
#define WP_W2  576  // 128 dwords: pack(f16(-L2E*W2[2k2][j]), f16(-L2E*W2[2k2+1][j]))
#define WS_TOT 704

__global__ void prep_kernel(const float* __restrict__ mh_W1, const float* __restrict__ mh_b1,
                            const float* __restrict__ mh_W2, const float* __restrict__ mh_b2,
                            const float* __restrict__ mh_W3, const float* __restrict__ mh_b3,
                            const float* __restrict__ ml_W1, const float* __restrict__ ml_b1,
                            const float* __restrict__ ml_W2, const float* __restrict__ ml_b2,
                            const float* __restrict__ ml_W3, const float* __restrict__ ml_b3,
                            float* __restrict__ ws, float* __restrict__ out_bins) {
    const int t = threadIdx.x;  // 64 threads
    for (int k = t; k < 128; k += 64) ws[WS_W1 + k] = -L2E * mh_W1[k];
    for (int k = t; k < 16;  k += 64) ws[WS_B1 + k] = -L2E * mh_b1[k];
    for (int k = t; k < 256; k += 64) ws[WS_W2 + k] = -L2E * mh_W2[k];
    for (int k = t; k < 16;  k += 64) ws[WS_B2 + k] = -L2E * mh_b2[k];
    for (int k = t; k < 16;  k += 64) ws[WS_W3 + k] =  L2E * mh_W3[k];
    if (t == 0) ws[WS_B3] = L2E * mh_b3[0];

    for (int k = t; k < 64; k += 64) {       // k = f2*16 + j
        const int f2 = k >> 4, j = k & 15;
        union { __fp16 h[2]; float f; } u;
        u.h[0] = (__fp16)(-L2E * mh_W1[(2 * f2)     * 16 + j]);
        u.h[1] = (__fp16)(-L2E * mh_W1[(2 * f2 + 1) * 16 + j]);
        ws[WP_W1 + k] = u.f;
    }
    for (int k = t; k < 128; k += 64) {      // k = k2*16 + j
        const int k2 = k >> 4, j = k & 15;
        union { __fp16 h[2]; float f; } u;
        u.h[0] = (__fp16)(-L2E * mh_W2[(2 * k2)     * 16 + j]);
        u.h[1] = (__fp16)(-L2E * mh_W2[(2 * k2 + 1) * 16 + j]);
        ws[WP_W2 + k] = u.f;
    }

    if (t < 40) {
        const float x = (float)(t + 1);
        float h1[16], h2[16];
        #pragma unroll
        for (int j = 0; j < 16; ++j)
            h1[j] = 1.0f / (1.0f + expf(-(x * ml_W1[j] + ml_b1[j])));
        #pragma unroll
        for (int j = 0; j < 16; ++j) {
            float a = ml_b2[j];
            #pragma unroll
            for (int k = 0; k < 16; ++k) a = fmaf(h1[k], ml_W2[k * 16 + j], a);
            h2[j] = 1.0f / (1.0f + expf(-a));
        }
        float phi = ml_b3[0];
        #pragma unroll
        for (int k = 0; k < 16; ++k) phi = fmaf(h2[k], ml_W3[k], phi);
        const float sc = expf(phi - 0.25f * x);
        ws[WS_TBL + t] = sc;
        if (t < NBINS) out_bins[t] = sc;  // dl2_scores term of output 1
    }
}

// Persistent-grid version (R10).  2048 blocks grid-stride over pairs,
// hand-rotated double buffer: iteration i+1's 6 global loads are issued
// BEFORE iteration i's compute (~2500 cyc of cover), amortizing wave
// entry latency 4x and cutting per-block global atomics 4x (57k total).
// Math = R9's verified dot2 body.  Tests the "fixed ~110us floor =
// entry-latency + epilogue-atomic" hypothesis; if flat, the floor is
// per-row (LDS atomic RMW / trans pipe) and next round attacks those.
struct PairIn {
    float4 a0, a1, b0, b1;
    int2 dl, ml;
};

__global__ __launch_bounds__(256) void main_kernel(
        const float4* __restrict__ x4,
        const int2* __restrict__ dl2p,
        const int2* __restrict__ ml2p,
        const float* __restrict__ ws,
        float2* __restrict__ out2,
        float* __restrict__ out_bins,
        int npair, int stride, int iters) {
    __shared__ float s_tbl[40];
    __shared__ float s_bins[4 * NBINS];
    const int tid = threadIdx.x;
    if (tid < 40) s_tbl[tid] = ws[WS_TBL + tid];
    if (tid < 4 * NBINS) s_bins[tid] = 0.0f;
    __syncthreads();

    float* myb = &s_bins[(tid >> 6) * NBINS];

    int p = blockIdx.x * 256 + tid;

    // preload iteration 0
    PairIn cur;
    {
        const int pc = (p < npair) ? p : 0;
        cur.a0 = x4[4 * pc + 0]; cur.a1 = x4[4 * pc + 1];
        cur.b0 = x4[4 * pc + 2]; cur.b1 = x4[4 * pc + 3];
        cur.dl = dl2p[pc];       cur.ml = ml2p[pc];
    }

    #pragma unroll 1
    for (int it = 0; it < iters; ++it) {
        // ---- issue next iteration's loads (fire-and-forget for now) ----
        PairIn nxt;
        const int pn = p + stride;
        if (it + 1 < iters) {
            const int pcn = (pn < npair) ? pn : 0;
            nxt.a0 = x4[4 * pcn + 0]; nxt.a1 = x4[4 * pcn + 1];
            nxt.b0 = x4[4 * pcn + 2]; nxt.b1 = x4[4 * pcn + 3];
            nxt.dl = dl2p[pcn];       nxt.ml = ml2p[pcn];
        }

        const bool active = (p < npair);
        const int2 dl = cur.dl;
        const int2 ml = cur.ml;

        // x packed to f16 pairs along the feature dim (4 pairs per row)
        h2t xp0[4], xp1[4];
        xp0[0] = pkx(cur.a0.x, cur.a0.y); xp0[1] = pkx(cur.a0.z, cur.a0.w);
        xp0[2] = pkx(cur.a1.x, cur.a1.y); xp0[3] = pkx(cur.a1.z, cur.a1.w);
        xp1[0] = pkx(cur.b0.x, cur.b0.y); xp1[1] = pkx(cur.b0.z, cur.b0.w);
        xp1[2] = pkx(cur.b1.x, cur.b1.y); xp1[3] = pkx(cur.b1.z, cur.b1.w);

        // ---- layer 1: 8 -> 16 via dot2 (weights prescaled by -log2e) ----
        float u0[16], u1[16];
        #pragma unroll
        for (int j = 0; j < 16; ++j) {
            const float b = ws[WS_B1 + j];
            u0[j] = b; u1[j] = b;
        }
        #pragma unroll
        for (int f2 = 0; f2 < 4; ++f2) {
            #pragma unroll
            for (int j = 0; j < 16; ++j) {
                const h2t w = asH2(ws[WP_W1 + f2 * 16 + j]);
                u0[j] = fdot2(xp0[f2], w, u0[j]);
                u1[j] = fdot2(xp1[f2], w, u1[j]);
            }
        }
        h2t hp0[8], hp1[8];
        #pragma unroll
        for (int k2 = 0; k2 < 8; ++k2) {
            const float h0a = RCPF(1.0f + EXP2F(u0[2 * k2]));
            const float h0b = RCPF(1.0f + EXP2F(u0[2 * k2 + 1]));
            const float h1a = RCPF(1.0f + EXP2F(u1[2 * k2]));
            const float h1b = RCPF(1.0f + EXP2F(u1[2 * k2 + 1]));
            hp0[k2] = pkx(h0a, h0b);
            hp1[k2] = pkx(h1a, h1b);
        }

        // ---- layer 2: 16 -> 16 via dot2 ----
        float v0[16], v1[16];
        #pragma unroll
        for (int j = 0; j < 16; ++j) {
            const float b = ws[WS_B2 + j];
            v0[j] = b; v1[j] = b;
        }
        #pragma unroll
        for (int k2 = 0; k2 < 8; ++k2) {
            #pragma unroll
            for (int j = 0; j < 16; ++j) {
                const h2t w = asH2(ws[WP_W2 + k2 * 16 + j]);
                v0[j] = fdot2(hp0[k2], w, v0[j]);
                v1[j] = fdot2(hp1[k2], w, v1[j]);
            }
        }

        // ---- layer 3 + psi (f32) ----
        float phi0 = ws[WS_B3], phi1 = phi0;   // prescaled by +log2e
        #pragma unroll
        for (int j = 0; j < 16; ++j) {
            const float w3 = ws[WS_W3 + j];    // prescaled by +log2e
            phi0 = fmaf(RCPF(1.0f + EXP2F(v0[j])), w3, phi0);
            phi1 = fmaf(RCPF(1.0f + EXP2F(v1[j])), w3, phi1);
        }
        const float sc0 = EXP2F(fmaf((float)dl.x, -0.25f * L2E, phi0));
        const float sc1 = EXP2F(fmaf((float)dl.y, -0.25f * L2E, phi1));

        // ---- epilogue for current pair ----
        if (active) {
            const int i0 = min(max(dl.x, 1), 40) - 1;
            const int i1 = min(max(dl.y, 1), 40) - 1;
            const float add0 = (dl.x == ml.x) ? s_tbl[i0] : 0.0f;
            const float add1 = (dl.y == ml.y) ? s_tbl[i1] : 0.0f;
            out2[p] = make_float2(sc0 + add0, sc1 + add1);
            if (dl.x >= 1 && dl.x <= NBINS) unsafeAtomicAdd(&myb[dl.x - 1], sc0);
            if (dl.y >= 1 && dl.y <= NBINS) unsafeAtomicAdd(&myb[dl.y - 1], sc1);
        }

        cur = nxt;
        p = pn;
    }

    __syncthreads();
    if (tid < NBINS) {
        const float bsum = s_bins[tid] + s_bins[NBINS + tid] +
                           s_bins[2 * NBINS + tid] + s_bins[3 * NBINS + tid];
        unsafeAtomicAdd(&out_bins[tid], bsum);
    }
}

extern "C" void kernel_launch(void* const* d_in, const int* in_sizes, int n_in,
                              void* d_out, int out_size, void* d_ws, size_t ws_size,
                              hipStream_t stream) {
    const int n = in_sizes[0] / 8;  // N rows (even)

    const float* x_feat = (const float*)d_in[0];
    const float* mh_W1  = (const float*)d_in[1];
    const float* mh_b1  = (const float*)d_in[2];
    const float* mh_W2  = (const float*)d_in[3];
    const float* mh_b2  = (const float*)d_in[4];
    const float* mh_W3  = (const float*)d_in[5];
    const float* mh_b3  = (const float*)d_in[6];
    const float* ml_W1  = (const float*)d_in[7];
    const float* ml_b1  = (const float*)d_in[8];
    const float* ml_W2  = (const float*)d_in[9];
    const float* ml_b2  = (const float*)d_in[10];
    const float* ml_W3  = (const float*)d_in[11];
    const float* ml_b3  = (const float*)d_in[12];
    const int* del_lens = (const int*)d_in[13];
    const int* mh_len   = (const int*)d_in[14];

    float* out      = (float*)d_out;
    float* out_bins = out + n;  // last 28 elements of d_out
    float* ws       = (float*)d_ws;

    prep_kernel<<<dim3(1), dim3(64), 0, stream>>>(
        mh_W1, mh_b1, mh_W2, mh_b2, mh_W3, mh_b3,
        ml_W1, ml_b1, ml_W2, ml_b2, ml_W3, ml_b3,
        ws, out_bins);

    const int npair = n / 2;
    int nblocks = 2048;                       // persistent grid, 8 blocks/CU
    const int needed = (npair + 255) / 256;
    if (needed < nblocks) nblocks = needed;
    const int stride = nblocks * 256;
    const int iters = (npair + stride - 1) / stride;
    main_kernel<<<dim3(nblocks), dim3(256), 0, stream>>>(
        (const float4*)x_feat, (const int2*)del_lens, (const int2*)mh_len,
        ws, (float2*)out, out_bins, npair, stride, iters);
}